// Round 7
// baseline (77.592 us; speedup 1.0000x reference)
//
#include <hip/hip_runtime.h>
#include <hip/hip_fp16.h>

#define CDIM  512
#define ROWS  65536
#define TILES 8
#define TR    64       // rows per tile; 128 rowblocks x 8 tiles x 64 rows = 65536

typedef _Float16 half8  __attribute__((ext_vector_type(8)));
typedef __fp16   fp16x2 __attribute__((ext_vector_type(2)));
typedef float    f32x16 __attribute__((ext_vector_type(16)));

// ---------------- K1a: v[j] = relu(Q . Wq[j,:] + bq[j]) * Wout[j/64] / 8 ----------------
__global__ void qproj_kernel(const float* __restrict__ Q, const float* __restrict__ Wq,
                             const float* __restrict__ bq, const float* __restrict__ Wout,
                             float* __restrict__ v) {
    __shared__ float qs[CDIM];
    const int t = threadIdx.x;
    qs[t] = Q[t]; qs[t + 256] = Q[t + 256];
    __syncthreads();
    const int jj  = t >> 4;
    const int sub = t & 15;
    const int j   = blockIdx.x * 16 + jj;
    const float4* w4 = (const float4*)(Wq + (size_t)j * CDIM + sub * 32);
    const float4* q4 = (const float4*)(qs + sub * 32);
    float s = 0.f;
    #pragma unroll
    for (int i = 0; i < 8; ++i) {
        float4 w = w4[i]; float4 q = q4[i];
        s = fmaf(w.x, q.x, s); s = fmaf(w.y, q.y, s);
        s = fmaf(w.z, q.z, s); s = fmaf(w.w, q.w, s);
    }
    s += __shfl_xor(s, 1); s += __shfl_xor(s, 2);
    s += __shfl_xor(s, 4); s += __shfl_xor(s, 8);
    if (sub == 0) {
        s += bq[j];
        s = fmaxf(s, 0.f);
        v[j] = s * Wout[j >> 6] * 0.125f;   // 1/sqrt(64) folded; bout dropped (shift-invariant)
    }
}

// ---------------- K1b: Wk -> fp16 B-fragments [jb 0..15][kc 0..31][lane 0..63][8 halfs] ----
// Fragment (jb,kc), lane l: B[k = kc*16 + (l>>5)*8 + e][j = jb*32 + (l&31)]
__global__ void wkfrag_kernel(const float* __restrict__ Wk, _Float16* __restrict__ Wkf) {
    const int gid = blockIdx.x * 256 + threadIdx.x;   // 32768 half8 slots
    const int jb  = gid >> 11;
    const int kc  = (gid >> 6) & 31;
    const int l   = gid & 63;
    const int j   = jb * 32 + (l & 31);
    const int k   = kc * 16 + (l >> 5) * 8;
    const float* src = Wk + (size_t)j * CDIM + k;
    float4 f0 = *(const float4*)(src);
    float4 f1 = *(const float4*)(src + 4);
    half8 h;
    h[0]=(_Float16)f0.x; h[1]=(_Float16)f0.y; h[2]=(_Float16)f0.z; h[3]=(_Float16)f0.w;
    h[4]=(_Float16)f1.x; h[5]=(_Float16)f1.y; h[6]=(_Float16)f1.z; h[7]=(_Float16)f1.w;
    *(half8*)(Wkf + (size_t)gid * 8) = h;
}

// ---------------- K2: 8-wave WG, B-in-regs (32 j/wave), NCLS=2, 64-row fp16 tiles ---------
// 256 WGs (1/CU). WG covers 512 rows as 8 tiles of 64. Wave w holds jb = cls*8+w resident.
// Per kc: two ds_read_b128 (rows l31, l31+32) feed two MFMAs sharing B[kc].
// Stage: reg-staged fp32->fp16 (cvt_pkrtz), XOR swizzle ((row&7)<<4) on write and read.
__global__ __launch_bounds__(512, 2) void score_kernel(
    const float* __restrict__ Kmat, const _Float16* __restrict__ Wkf,
    const float* __restrict__ bk, const float* __restrict__ v,
    float* __restrict__ partial2)
{
    __shared__ alignas(16) char stage[2][TR * 1024];   // 2 x 64KB fp16 (row stride 1KB)
    __shared__ float scratch2[2][8][TR];               // 4KB

    const int tid  = threadIdx.x;
    const int lane = tid & 63;
    const int wave = tid >> 6;
    const int l31  = lane & 31;
    const int lhi  = lane >> 5;

    const int bid      = blockIdx.x;
    const int rowblock = (bid & 7) * 16 + (bid >> 4);   // XCD-pairing: partners differ by bid+8
    const int cls      = (bid >> 3) & 1;
    const int jb       = cls * 8 + wave;

    // ---- B prologue: 32 resident fragments (full depth, this wave's 32 j's) ----
    half8 B[32];
    const half8* bsrc = (const half8*)Wkf + (size_t)jb * 2048 + lane;
    #pragma unroll
    for (int kc = 0; kc < 32; ++kc) B[kc] = bsrc[kc * 64];
    const int jmy = jb * 32 + l31;
    const float bj = bk[jmy];
    const float vj = v[jmy];

    const int rowbase = rowblock * (TILES * TR);
    float* pbase = partial2 + (size_t)cls * ROWS;

    // staging geometry: thread -> (row srow, float4-col group sc8); half-batch h covers 32 floats
    const int srow = tid >> 3;          // 0..63
    const int sc8  = tid & 7;           // 0..7
    const int swz  = (srow & 7) << 4;
    const char* gbase = (const char*)(Kmat + (size_t)(rowbase + srow) * CDIM + sc8 * 64);
    char* lbase0;  // per-tile computed

    // ---- prologue: stage tile 0, both halves ----
    #pragma unroll
    for (int h = 0; h < 2; ++h) {
        float4 L[8];
        #pragma unroll
        for (int i = 0; i < 8; ++i)
            L[i] = *(const float4*)(gbase + (size_t)h * 128 + i * 16);
        #pragma unroll
        for (int s = 0; s < 4; ++s) {
            union { fp16x2 h2[4]; half8 h8; } u;
            u.h2[0] = __builtin_amdgcn_cvt_pkrtz(L[2*s].x,   L[2*s].y);
            u.h2[1] = __builtin_amdgcn_cvt_pkrtz(L[2*s].z,   L[2*s].w);
            u.h2[2] = __builtin_amdgcn_cvt_pkrtz(L[2*s+1].x, L[2*s+1].y);
            u.h2[3] = __builtin_amdgcn_cvt_pkrtz(L[2*s+1].z, L[2*s+1].w);
            *(half8*)(&stage[0][srow * 1024 + ((sc8 * 128 + h * 64 + s * 16) ^ swz)]) = u.h8;
        }
    }
    __syncthreads();

    for (int t = 0; t < TILES; ++t) {
        const int cur = t & 1;
        const bool pf = (t + 1 < TILES);
        const char* sb = &stage[cur][0];
        char* db = &stage[cur ^ 1][0];
        const char* gt = gbase + (size_t)(t + 1) * TR * CDIM * 4;

        // cross-wave summer for tile t-1
        if (t > 0 && tid < TR) {
            const int pt = (t - 1) & 1;
            float s = 0.f;
            #pragma unroll
            for (int w = 0; w < 8; ++w) s += scratch2[pt][w][tid];
            pbase[rowbase + (t - 1) * TR + tid] = s;
        }

        f32x16 acc0, acc1;
        #pragma unroll
        for (int r = 0; r < 16; ++r) { acc0[r] = 0.f; acc1[r] = 0.f; }

        // ---- issue h0 loads for t+1 ----
        float4 L[8];
        if (pf) {
            #pragma unroll
            for (int i = 0; i < 8; ++i) L[i] = *(const float4*)(gt + i * 16);
        }
        __builtin_amdgcn_sched_barrier(0);

        // ---- kc 0..15 ----
        const int rswz = (l31 & 7) << 4;
        #pragma unroll
        for (int kc = 0; kc < 16; ++kc) {
            const int off = (kc * 32 + lhi * 16) ^ rswz;
            half8 a0 = *(const half8*)(sb + l31 * 1024 + off);
            half8 a1 = *(const half8*)(sb + (32 + l31) * 1024 + off);
            acc0 = __builtin_amdgcn_mfma_f32_32x32x16_f16(a0, B[kc], acc0, 0, 0, 0);
            acc1 = __builtin_amdgcn_mfma_f32_32x32x16_f16(a1, B[kc], acc1, 0, 0, 0);
        }

        // ---- write h0 (loads have had the whole kc0-loop to land), issue h1 ----
        if (pf) {
            #pragma unroll
            for (int s = 0; s < 4; ++s) {
                union { fp16x2 h2[4]; half8 h8; } u;
                u.h2[0] = __builtin_amdgcn_cvt_pkrtz(L[2*s].x,   L[2*s].y);
                u.h2[1] = __builtin_amdgcn_cvt_pkrtz(L[2*s].z,   L[2*s].w);
                u.h2[2] = __builtin_amdgcn_cvt_pkrtz(L[2*s+1].x, L[2*s+1].y);
                u.h2[3] = __builtin_amdgcn_cvt_pkrtz(L[2*s+1].z, L[2*s+1].w);
                *(half8*)(db + srow * 1024 + ((sc8 * 128 + s * 16) ^ swz)) = u.h8;
            }
            #pragma unroll
            for (int i = 0; i < 8; ++i) L[i] = *(const float4*)(gt + 128 + i * 16);
        }
        __builtin_amdgcn_sched_barrier(0);

        // ---- kc 16..31 ----
        #pragma unroll
        for (int kc = 16; kc < 32; ++kc) {
            const int off = (kc * 32 + lhi * 16) ^ rswz;
            half8 a0 = *(const half8*)(sb + l31 * 1024 + off);
            half8 a1 = *(const half8*)(sb + (32 + l31) * 1024 + off);
            acc0 = __builtin_amdgcn_mfma_f32_32x32x16_f16(a0, B[kc], acc0, 0, 0, 0);
            acc1 = __builtin_amdgcn_mfma_f32_32x32x16_f16(a1, B[kc], acc1, 0, 0, 0);
        }

        // ---- write h1 ----
        if (pf) {
            #pragma unroll
            for (int s = 0; s < 4; ++s) {
                union { fp16x2 h2[4]; half8 h8; } u;
                u.h2[0] = __builtin_amdgcn_cvt_pkrtz(L[2*s].x,   L[2*s].y);
                u.h2[1] = __builtin_amdgcn_cvt_pkrtz(L[2*s].z,   L[2*s].w);
                u.h2[2] = __builtin_amdgcn_cvt_pkrtz(L[2*s+1].x, L[2*s+1].y);
                u.h2[3] = __builtin_amdgcn_cvt_pkrtz(L[2*s+1].z, L[2*s+1].w);
                *(half8*)(db + srow * 1024 + ((sc8 * 128 + 64 + s * 16) ^ swz)) = u.h8;
            }
        }

        // ---- epilogue: per row-group, relu + v-weight + fold-tree over 32 j-lanes ----
        #pragma unroll
        for (int g = 0; g < 2; ++g) {
            float x[16];
            #pragma unroll
            for (int r = 0; r < 16; ++r) {
                float a = (g == 0) ? acc0[r] : acc1[r];
                x[r] = fmaxf(a + bj, 0.f) * vj;
            }
            float q0[8];
            #pragma unroll
            for (int i = 0; i < 8; ++i) {
                const bool b = lane & 1;
                float keep = b ? x[i + 8] : x[i];
                float send = b ? x[i] : x[i + 8];
                q0[i] = keep + __shfl_xor(send, 1);
            }
            float q1[4];
            #pragma unroll
            for (int i = 0; i < 4; ++i) {
                const bool b = lane & 2;
                float keep = b ? q0[i + 4] : q0[i];
                float send = b ? q0[i] : q0[i + 4];
                q1[i] = keep + __shfl_xor(send, 2);
            }
            float q2[2];
            #pragma unroll
            for (int i = 0; i < 2; ++i) {
                const bool b = lane & 4;
                float keep = b ? q1[i + 2] : q1[i];
                float send = b ? q1[i] : q1[i + 2];
                q2[i] = keep + __shfl_xor(send, 4);
            }
            float q3;
            {
                const bool b = lane & 8;
                float keep = b ? q2[1] : q2[0];
                float send = b ? q2[0] : q2[1];
                q3 = keep + __shfl_xor(send, 8);
            }
            float s = q3 + __shfl_xor(q3, 16);
            if (l31 < 16) {
                const int r   = ((l31 & 1) << 3) | ((l31 & 2) << 1) | ((l31 & 4) >> 1) | ((l31 & 8) >> 3);
                const int row = (r & 3) + 8 * (r >> 2) + 4 * lhi;
                scratch2[cur][wave][g * 32 + row] = s;
            }
        }

        __syncthreads();
    }

    // drain: summer for the last tile
    if (tid < TR) {
        const int pt = (TILES - 1) & 1;
        float s = 0.f;
        #pragma unroll
        for (int w = 0; w < 8; ++w) s += scratch2[pt][w][tid];
        pbase[rowbase + (TILES - 1) * TR + tid] = s;
    }
}

// ---------------- K3: merge 2 classes, store logits, per-block exp-sum ----------------
__global__ void expsum_kernel(const float* __restrict__ partial2, float* __restrict__ logits,
                              float* __restrict__ blocksum) {
    __shared__ float red[256];
    const int t = threadIdx.x;
    const int row = blockIdx.x * 256 + t;
    const float lg = partial2[row] + partial2[ROWS + row];
    logits[row] = lg;
    red[t] = expf(lg);
    __syncthreads();
    for (int s = 128; s > 0; s >>= 1) {
        if (t < s) red[t] += red[t + s];
        __syncthreads();
    }
    if (t == 0) blocksum[blockIdx.x] = red[0];
}

// ---------------- K4: normalize ----------------
__global__ void norm_kernel(const float* __restrict__ logits, const float* __restrict__ blocksum,
                            float* __restrict__ out) {
    __shared__ float red[256];
    const int t = threadIdx.x;
    red[t] = blocksum[t];
    __syncthreads();
    for (int s = 128; s > 0; s >>= 1) {
        if (t < s) red[t] += red[t + s];
        __syncthreads();
    }
    const float zinv = 1.0f / red[0];
    const int i = blockIdx.x * 256 + t;
    out[i] = expf(logits[i]) * zinv;
}

extern "C" void kernel_launch(void* const* d_in, const int* in_sizes, int n_in,
                              void* d_out, int out_size, void* d_ws, size_t ws_size,
                              hipStream_t stream) {
    const float* Q    = (const float*)d_in[0];
    const float* Kmat = (const float*)d_in[1];
    const float* Wq   = (const float*)d_in[2];
    const float* bq   = (const float*)d_in[3];
    const float* Wk   = (const float*)d_in[4];
    const float* bk   = (const float*)d_in[5];
    const float* Wout = (const float*)d_in[6];
    float* out = (float*)d_out;

    char* ws = (char*)d_ws;
    _Float16* Wkf   = (_Float16*)(ws);                // 524288 B
    float* v        = (float*)(ws + 524288);          //   2048 B
    float* partial2 = (float*)(ws + 526336);          // 524288 B (2 classes x 65536)
    float* logits   = (float*)(ws + 1050624);         // 262144 B
    float* blocksum = (float*)(ws + 1312768);         //   1024 B

    hipLaunchKernelGGL(qproj_kernel,  dim3(32),   dim3(256), 0, stream, Q, Wq, bq, Wout, v);
    hipLaunchKernelGGL(wkfrag_kernel, dim3(128),  dim3(256), 0, stream, Wk, Wkf);
    hipLaunchKernelGGL(score_kernel,  dim3(256),  dim3(512), 0, stream, Kmat, Wkf, bk, v, partial2);
    hipLaunchKernelGGL(expsum_kernel, dim3(256),  dim3(256), 0, stream, partial2, logits, blocksum);
    hipLaunchKernelGGL(norm_kernel,   dim3(256),  dim3(256), 0, stream, logits, blocksum, out);
}